// Round 1
// baseline (2345.124 us; speedup 1.0000x reference)
//
#include <hip/hip_runtime.h>
#include <math.h>

#define S 4
#define G 3
#define NN 20000
#define EE 320000
#define D 64
#define SG (S*G)

static __device__ __forceinline__ float sigmf(float x){ return 1.0f/(1.0f + __expf(-x)); }

// ---------------- CSR build ----------------

__global__ __launch_bounds__(256) void count_kernel(const int* __restrict__ ei, int* __restrict__ deg){
    int idx = blockIdx.x*256 + threadIdx.x;
    const int tot = SG*EE;
    if (idx >= tot) return;
    int sg = idx / EE, e = idx - sg*EE;
    int dst = ei[(sg*2 + 1)*EE + e];
    atomicAdd(&deg[sg*NN + dst], 1);
}

__global__ __launch_bounds__(256) void scan_kernel(const int* __restrict__ deg,
                                                   int* __restrict__ off,
                                                   int* __restrict__ cursor){
    const int CH = (NN + 255)/256; // 79
    int sg = blockIdx.x, t = threadIdx.x;
    int base = sg*NN, obase = sg*(NN+1);
    int lo = t*CH, hi = min(lo+CH, NN);
    int s = 0;
    for (int i = lo; i < hi; ++i) s += deg[base+i];
    __shared__ int sums[256];
    sums[t] = s; __syncthreads();
    for (int ofs = 1; ofs < 256; ofs <<= 1){
        int v = (t >= ofs) ? sums[t-ofs] : 0;
        __syncthreads();
        sums[t] += v;
        __syncthreads();
    }
    int start = sums[t] - s;  // exclusive prefix at chunk start
    for (int i = lo; i < hi; ++i){
        off[obase+i] = start;
        cursor[base+i] = start;
        start += deg[base+i];
    }
    if (lo < NN && hi == NN) off[obase+NN] = start; // == EE
}

__global__ __launch_bounds__(256) void fill_kernel(const int* __restrict__ ei,
                                                   int* __restrict__ cursor,
                                                   int* __restrict__ csr){
    int idx = blockIdx.x*256 + threadIdx.x;
    const int tot = SG*EE;
    if (idx >= tot) return;
    int sg = idx / EE, e = idx - sg*EE;
    int src = ei[(sg*2 + 0)*EE + e];
    int dst = ei[(sg*2 + 1)*EE + e];
    int slot = atomicAdd(&cursor[sg*NN + dst], 1);
    csr[(size_t)sg*EE + slot] = src;
}

// ---------------- SAGE layer: aggregate(mean via CSR) + GEMM + tanh ----------------
// out[sg][i][c] = tanh( mean[i][:] @ Wl[g] + in[i][:] @ Wr[g] + b[g] )

#define LDT 68   // padded leading dim for transposed [k][r] tiles (68%4==0 -> b128 aligned)

__device__ __forceinline__ void gemm_pass(const float* __restrict__ sA,
                                          const float* __restrict__ sW,
                                          int r0, int c0, float acc[4][4]){
    #pragma unroll 4
    for (int k = 0; k < 64; ++k){
        float4 a4 = *(const float4*)&sA[k*LDT + r0];
        float4 w4 = *(const float4*)&sW[k*64 + c0];
        float a[4] = {a4.x, a4.y, a4.z, a4.w};
        float w[4] = {w4.x, w4.y, w4.z, w4.w};
        #pragma unroll
        for (int i = 0; i < 4; ++i)
            #pragma unroll
            for (int j = 0; j < 4; ++j)
                acc[i][j] = fmaf(a[i], w[j], acc[i][j]);
    }
}

__global__ __launch_bounds__(256) void layer_kernel(const float* __restrict__ in,
                                                    const int* __restrict__ off,
                                                    const int* __restrict__ csr,
                                                    const float* __restrict__ Wl,
                                                    const float* __restrict__ Wr,
                                                    const float* __restrict__ bias,
                                                    float* __restrict__ out){
    __shared__ float sW[64*64];      // 16 KB (Wl then Wr)
    __shared__ float sMeanT[64*LDT]; // 17 KB  [k][r]
    __shared__ float sXT[64*LDT];    // 17 KB  [k][r]

    int tile = blockIdx.x, sg = blockIdx.y;
    int g = sg % G;
    int tid = threadIdx.x;
    int row0 = tile*64;
    const float* inb = in + (size_t)sg*NN*D;

    // stage Wl
    for (int idx = tid; idx < 64*64; idx += 256) sW[idx] = Wl[g*64*64 + idx];
    // stage x tile transposed
    for (int idx = tid; idx < 64*64; idx += 256){
        int r = idx >> 6, f = idx & 63;
        int i = row0 + r;
        sXT[f*LDT + r] = (i < NN) ? inb[(size_t)i*D + f] : 0.0f;
    }
    // aggregate mean over in-neighbors: wave per row, lane = feature
    {
        int wave = tid >> 6, lane = tid & 63;
        const int* offb = off + sg*(NN+1);
        const int* csrb = csr + (size_t)sg*EE;
        for (int j = 0; j < 16; ++j){
            int r = wave*16 + j;
            int i = row0 + r;
            float acc = 0.0f;
            int cnt = 0;
            if (i < NN){
                int a = offb[i], b = offb[i+1];
                cnt = b - a;
                for (int p = a; p < b; ++p){
                    int srcn = csrb[p];
                    acc += inb[(size_t)srcn*D + lane];
                }
            }
            float inv = (cnt > 0) ? (1.0f/(float)cnt) : 0.0f;
            sMeanT[lane*LDT + r] = acc * inv;
        }
    }
    __syncthreads();

    int tx = tid & 15, ty = tid >> 4;
    int c0 = tx*4, r0 = ty*4;
    float acc[4][4];
    #pragma unroll
    for (int i = 0; i < 4; ++i)
        #pragma unroll
        for (int j = 0; j < 4; ++j) acc[i][j] = 0.0f;

    gemm_pass(sMeanT, sW, r0, c0, acc);   // mean @ Wl
    __syncthreads();                       // readers of sW done
    for (int idx = tid; idx < 64*64; idx += 256) sW[idx] = Wr[g*64*64 + idx];
    __syncthreads();
    gemm_pass(sXT, sW, r0, c0, acc);      // x @ Wr

    float4 b4 = *(const float4*)&bias[g*64 + c0];
    float bv[4] = {b4.x, b4.y, b4.z, b4.w};
    float* outb = out + (size_t)sg*NN*D;
    #pragma unroll
    for (int i = 0; i < 4; ++i){
        int r = row0 + r0 + i;
        if (r < NN){
            float4 o;
            o.x = tanhf(acc[i][0] + bv[0]);
            o.y = tanhf(acc[i][1] + bv[1]);
            o.z = tanhf(acc[i][2] + bv[2]);
            o.w = tanhf(acc[i][3] + bv[3]);
            *(float4*)&outb[(size_t)r*D + c0] = o;
        }
    }
}

// ---------------- LSTM weight prep: Wcat[k][gate], bc = bih+bhh ----------------

__global__ __launch_bounds__(256) void wprep_kernel(const float* __restrict__ Wih,
                                                    const float* __restrict__ Whh,
                                                    const float* __restrict__ bih,
                                                    const float* __restrict__ bhh,
                                                    float* __restrict__ Wcat,
                                                    float* __restrict__ bc){
    int idx = blockIdx.x*256 + threadIdx.x;
    if (idx < 128*256){
        int k = idx >> 8, gc = idx & 255;
        Wcat[idx] = (k < 64) ? Wih[gc*64 + k] : Whh[gc*64 + (k - 64)];
    }
    if (idx < 256) bc[idx] = bih[idx] + bhh[idx];
}

// ---------------- LSTM: 3 steps fused, c in regs, h in LDS ----------------
// batch b = s*NN + n ; x_t[b] = h2[s][g=t][n][:]

__global__ __launch_bounds__(256) void lstm_kernel(const float* __restrict__ h2,
                                                   const float* __restrict__ Wcat,
                                                   const float* __restrict__ bc,
                                                   float* __restrict__ out){
    __shared__ float sZ[128*LDT]; // [k][r], k<64: x_t, k>=64: h_{t-1}; ~34.8 KB
    int tid = threadIdx.x;
    int b0 = blockIdx.x * 64;
    int tx = tid & 15, ty = tid >> 4;
    int f0 = tx*4, r0 = ty*4;

    float c[4][4];
    #pragma unroll
    for (int i = 0; i < 4; ++i)
        #pragma unroll
        for (int j = 0; j < 4; ++j) c[i][j] = 0.0f;

    float bb[4][4];
    #pragma unroll
    for (int T = 0; T < 4; ++T){
        float4 t4 = *(const float4*)&bc[T*64 + f0];
        bb[T][0] = t4.x; bb[T][1] = t4.y; bb[T][2] = t4.z; bb[T][3] = t4.w;
    }

    for (int t = 0; t < G; ++t){
        // stage x_t transposed into sZ[0..63][r]
        for (int idx = tid; idx < 64*64; idx += 256){
            int r = idx >> 6, f = idx & 63;
            int b = b0 + r;
            int s = b / NN, n = b - s*NN;
            sZ[f*LDT + r] = h2[((size_t)(s*G + t)*NN + n)*D + f];
        }
        __syncthreads();

        int kmax = (t == 0) ? 64 : 128;  // h_0 == 0, skip h-half
        float acc[4][4][4]; // [gate-type T][row i][feat j]
        #pragma unroll
        for (int T = 0; T < 4; ++T)
            #pragma unroll
            for (int i = 0; i < 4; ++i)
                #pragma unroll
                for (int j = 0; j < 4; ++j) acc[T][i][j] = 0.0f;

        #pragma unroll 2
        for (int k = 0; k < kmax; ++k){
            float4 za4 = *(const float4*)&sZ[k*LDT + r0];
            float za[4] = {za4.x, za4.y, za4.z, za4.w};
            #pragma unroll
            for (int T = 0; T < 4; ++T){
                float4 w4 = *(const float4*)&Wcat[k*256 + T*64 + f0];
                float w[4] = {w4.x, w4.y, w4.z, w4.w};
                #pragma unroll
                for (int i = 0; i < 4; ++i)
                    #pragma unroll
                    for (int j = 0; j < 4; ++j)
                        acc[T][i][j] = fmaf(za[i], w[j], acc[T][i][j]);
            }
        }
        __syncthreads(); // everyone done reading sZ before h overwrite

        float hn[4][4];
        #pragma unroll
        for (int i = 0; i < 4; ++i)
            #pragma unroll
            for (int j = 0; j < 4; ++j){
                float ig = sigmf(acc[0][i][j] + bb[0][j]);
                float fg = sigmf(acc[1][i][j] + bb[1][j]);
                float gg = tanhf(acc[2][i][j] + bb[2][j]);
                float og = sigmf(acc[3][i][j] + bb[3][j]);
                float cn = fg*c[i][j] + ig*gg;
                c[i][j] = cn;
                float hv = og * tanhf(cn);
                hn[i][j] = hv;
                if (t < G-1) sZ[(64 + f0 + j)*LDT + (r0 + i)] = hv;
            }
        if (t == G-1){
            #pragma unroll
            for (int i = 0; i < 4; ++i){
                float4 o; o.x = hn[i][0]; o.y = hn[i][1]; o.z = hn[i][2]; o.w = hn[i][3];
                *(float4*)&out[(size_t)(b0 + r0 + i)*D + f0] = o;
            }
        }
        // next staging writes only the x-half; h-writes become visible at the
        // post-staging __syncthreads before anyone reads them.
    }
}

// ---------------- host ----------------

extern "C" void kernel_launch(void* const* d_in, const int* in_sizes, int n_in,
                              void* d_out, int out_size, void* d_ws, size_t ws_size,
                              hipStream_t stream) {
    const float* x   = (const float*)d_in[0];
    const int*   ei  = (const int*)  d_in[1];
    const float* W1l = (const float*)d_in[2];
    const float* W1r = (const float*)d_in[3];
    const float* b1  = (const float*)d_in[4];
    const float* W2l = (const float*)d_in[5];
    const float* W2r = (const float*)d_in[6];
    const float* b2  = (const float*)d_in[7];
    const float* Wih = (const float*)d_in[8];
    const float* Whh = (const float*)d_in[9];
    const float* bih = (const float*)d_in[10];
    const float* bhh = (const float*)d_in[11];
    float* out = (float*)d_out;

    char* ws = (char*)d_ws;
    size_t cur = 0;
    auto alloc = [&](size_t bytes)->void*{
        cur = (cur + 255) & ~(size_t)255;
        void* p = ws + cur; cur += bytes; return p;
    };
    int*   deg    = (int*)  alloc((size_t)SG*NN*4);
    int*   off    = (int*)  alloc((size_t)SG*(NN+1)*4);
    int*   cursor = (int*)  alloc((size_t)SG*NN*4);
    int*   csr    = (int*)  alloc((size_t)SG*EE*4);
    float* h1     = (float*)alloc((size_t)SG*NN*D*4);
    float* h2     = (float*)alloc((size_t)SG*NN*D*4);
    float* Wcat   = (float*)alloc((size_t)128*256*4);
    float* bc     = (float*)alloc((size_t)256*4);
    (void)ws_size; (void)in_sizes; (void)n_in; (void)out_size;
    // total ws use ~141.3 MB

    hipMemsetAsync(deg, 0, (size_t)SG*NN*4, stream);

    const int totE = SG*EE;
    count_kernel<<<(totE + 255)/256, 256, 0, stream>>>(ei, deg);
    scan_kernel <<<SG, 256, 0, stream>>>(deg, off, cursor);
    fill_kernel <<<(totE + 255)/256, 256, 0, stream>>>(ei, cursor, csr);

    dim3 lgrid((NN + 63)/64, SG);
    layer_kernel<<<lgrid, 256, 0, stream>>>(x,  off, csr, W1l, W1r, b1, h1);
    layer_kernel<<<lgrid, 256, 0, stream>>>(h1, off, csr, W2l, W2r, b2, h2);

    wprep_kernel<<<128, 256, 0, stream>>>(Wih, Whh, bih, bhh, Wcat, bc);
    lstm_kernel <<<(S*NN)/64, 256, 0, stream>>>(h2, Wcat, bc, out);
}

// Round 2
// 1185.079 us; speedup vs baseline: 1.9789x; 1.9789x over previous
//
#include <hip/hip_runtime.h>
#include <math.h>

#define S 4
#define G 3
#define NN 20000
#define EE 320000
#define D 64
#define SG (S*G)

static __device__ __forceinline__ float sigmf(float x){ return 1.0f/(1.0f + __expf(-x)); }

// ---------------- CSR build ----------------

__global__ __launch_bounds__(256) void count_kernel(const int* __restrict__ ei, int* __restrict__ deg){
    int idx = blockIdx.x*256 + threadIdx.x;
    const int tot = SG*EE;
    if (idx >= tot) return;
    int sg = idx / EE, e = idx - sg*EE;
    int dst = ei[(sg*2 + 1)*EE + e];
    atomicAdd(&deg[sg*NN + dst], 1);
}

__global__ __launch_bounds__(256) void scan_kernel(const int* __restrict__ deg,
                                                   int* __restrict__ off,
                                                   int* __restrict__ cursor){
    const int CH = (NN + 255)/256; // 79
    int sg = blockIdx.x, t = threadIdx.x;
    int base = sg*NN, obase = sg*(NN+1);
    int lo = t*CH, hi = min(lo+CH, NN);
    int s = 0;
    for (int i = lo; i < hi; ++i) s += deg[base+i];
    __shared__ int sums[256];
    sums[t] = s; __syncthreads();
    for (int ofs = 1; ofs < 256; ofs <<= 1){
        int v = (t >= ofs) ? sums[t-ofs] : 0;
        __syncthreads();
        sums[t] += v;
        __syncthreads();
    }
    int start = sums[t] - s;  // exclusive prefix at chunk start
    for (int i = lo; i < hi; ++i){
        off[obase+i] = start;
        cursor[base+i] = start;
        start += deg[base+i];
    }
    if (lo < NN && hi == NN) off[obase+NN] = start; // == EE
}

__global__ __launch_bounds__(256) void fill_kernel(const int* __restrict__ ei,
                                                   int* __restrict__ cursor,
                                                   int* __restrict__ csr){
    int idx = blockIdx.x*256 + threadIdx.x;
    const int tot = SG*EE;
    if (idx >= tot) return;
    int sg = idx / EE, e = idx - sg*EE;
    int src = ei[(sg*2 + 0)*EE + e];
    int dst = ei[(sg*2 + 1)*EE + e];
    int slot = atomicAdd(&cursor[sg*NN + dst], 1);
    csr[(size_t)sg*EE + slot] = src;
}

// ---------------- SAGE layer: aggregate(mean via CSR) + GEMM + tanh ----------------
// out[sg][i][c] = tanh( mean[i][:] @ Wl[g] + in[i][:] @ Wr[g] + b[g] )

#define LDT 68   // padded leading dim for transposed [k][r] tiles (68%4==0 -> b128 aligned)

__device__ __forceinline__ void gemm_pass(const float* __restrict__ sA,
                                          const float* __restrict__ sW,
                                          int r0, int c0, float acc[4][4]){
    #pragma unroll 4
    for (int k = 0; k < 64; ++k){
        float4 a4 = *(const float4*)&sA[k*LDT + r0];
        float4 w4 = *(const float4*)&sW[k*64 + c0];
        float a[4] = {a4.x, a4.y, a4.z, a4.w};
        float w[4] = {w4.x, w4.y, w4.z, w4.w};
        #pragma unroll
        for (int i = 0; i < 4; ++i)
            #pragma unroll
            for (int j = 0; j < 4; ++j)
                acc[i][j] = fmaf(a[i], w[j], acc[i][j]);
    }
}

__global__ __launch_bounds__(256) void layer_kernel(const float* __restrict__ in,
                                                    const int* __restrict__ off,
                                                    const int* __restrict__ csr,
                                                    const float* __restrict__ Wl,
                                                    const float* __restrict__ Wr,
                                                    const float* __restrict__ bias,
                                                    float* __restrict__ out){
    __shared__ float sW[64*64];      // 16 KB (Wl then Wr)
    __shared__ float sMeanT[64*LDT]; // 17 KB  [k][r]
    __shared__ float sXT[64*LDT];    // 17 KB  [k][r]

    int tile = blockIdx.x, sg = blockIdx.y;
    int g = sg % G;
    int tid = threadIdx.x;
    int row0 = tile*64;
    const float* inb = in + (size_t)sg*NN*D;

    // stage Wl (float4)
    for (int idx = tid; idx < 64*16; idx += 256)
        *(float4*)&sW[idx*4] = *(const float4*)&Wl[g*64*64 + idx*4];
    // stage x tile transposed: float4 global loads, scalar LDS writes
    for (int idx = tid; idx < 64*16; idx += 256){
        int r = idx >> 4, fq = idx & 15;
        int i = row0 + r;
        float4 v = {0,0,0,0};
        if (i < NN) v = *(const float4*)&inb[(size_t)i*D + fq*4];
        sXT[(fq*4+0)*LDT + r] = v.x;
        sXT[(fq*4+1)*LDT + r] = v.y;
        sXT[(fq*4+2)*LDT + r] = v.z;
        sXT[(fq*4+3)*LDT + r] = v.w;
    }
    // aggregate mean over in-neighbors: wave per row, 4 neighbor-groups x 16 lanes x float4
    {
        int wave = tid >> 6, lane = tid & 63;
        int grp = lane >> 4, fq = lane & 15, fb = fq*4;
        const int* offb = off + sg*(NN+1);
        const int* csrb = csr + (size_t)sg*EE;
        int i0 = row0 + wave*16;
        // offsets for this wave's 16 rows (+1), one coalesced load
        int ov = offb[min(i0 + lane, NN)];
        for (int r = 0; r < 16; ++r){
            int a   = __shfl(ov, r,   64);
            int b   = __shfl(ov, r+1, 64);
            int deg = b - a;
            float4 acc = {0.0f, 0.0f, 0.0f, 0.0f};
            for (int base = 0; base < deg; base += 64){
                int m = min(deg - base, 64);
                int cv = (lane < m) ? csrb[a + base + lane] : 0;
                int nit = (m + 7) >> 3;
                for (int it = 0; it < nit; ++it){
                    int p0 = it*8 + grp;
                    int p1 = it*8 + 4 + grp;
                    int n0 = __shfl(cv, p0, 64);
                    int n1 = __shfl(cv, p1, 64);
                    float4 v0 = {0,0,0,0}, v1 = {0,0,0,0};
                    if (p0 < m) v0 = *(const float4*)&inb[(size_t)n0*D + fb];
                    if (p1 < m) v1 = *(const float4*)&inb[(size_t)n1*D + fb];
                    acc.x += v0.x + v1.x;
                    acc.y += v0.y + v1.y;
                    acc.z += v0.z + v1.z;
                    acc.w += v0.w + v1.w;
                }
            }
            // reduce across 4 neighbor-groups
            acc.x += __shfl_xor(acc.x, 16, 64);
            acc.y += __shfl_xor(acc.y, 16, 64);
            acc.z += __shfl_xor(acc.z, 16, 64);
            acc.w += __shfl_xor(acc.w, 16, 64);
            acc.x += __shfl_xor(acc.x, 32, 64);
            acc.y += __shfl_xor(acc.y, 32, 64);
            acc.z += __shfl_xor(acc.z, 32, 64);
            acc.w += __shfl_xor(acc.w, 32, 64);
            float inv = (deg > 0) ? (1.0f/(float)deg) : 0.0f;
            if (grp == 0){
                int tr = wave*16 + r;
                sMeanT[(fb+0)*LDT + tr] = acc.x * inv;
                sMeanT[(fb+1)*LDT + tr] = acc.y * inv;
                sMeanT[(fb+2)*LDT + tr] = acc.z * inv;
                sMeanT[(fb+3)*LDT + tr] = acc.w * inv;
            }
        }
    }
    __syncthreads();

    int tx = tid & 15, ty = tid >> 4;
    int c0 = tx*4, r0 = ty*4;
    float acc[4][4];
    #pragma unroll
    for (int i = 0; i < 4; ++i)
        #pragma unroll
        for (int j = 0; j < 4; ++j) acc[i][j] = 0.0f;

    gemm_pass(sMeanT, sW, r0, c0, acc);   // mean @ Wl
    __syncthreads();                       // readers of sW done
    for (int idx = tid; idx < 64*16; idx += 256)
        *(float4*)&sW[idx*4] = *(const float4*)&Wr[g*64*64 + idx*4];
    __syncthreads();
    gemm_pass(sXT, sW, r0, c0, acc);      // x @ Wr

    float4 b4 = *(const float4*)&bias[g*64 + c0];
    float bv[4] = {b4.x, b4.y, b4.z, b4.w};
    float* outb = out + (size_t)sg*NN*D;
    #pragma unroll
    for (int i = 0; i < 4; ++i){
        int r = row0 + r0 + i;
        if (r < NN){
            float4 o;
            o.x = tanhf(acc[i][0] + bv[0]);
            o.y = tanhf(acc[i][1] + bv[1]);
            o.z = tanhf(acc[i][2] + bv[2]);
            o.w = tanhf(acc[i][3] + bv[3]);
            *(float4*)&outb[(size_t)r*D + c0] = o;
        }
    }
}

// ---------------- LSTM weight prep: Wcat[k][gate], bc = bih+bhh ----------------

__global__ __launch_bounds__(256) void wprep_kernel(const float* __restrict__ Wih,
                                                    const float* __restrict__ Whh,
                                                    const float* __restrict__ bih,
                                                    const float* __restrict__ bhh,
                                                    float* __restrict__ Wcat,
                                                    float* __restrict__ bc){
    int idx = blockIdx.x*256 + threadIdx.x;
    if (idx < 128*256){
        int k = idx >> 8, gc = idx & 255;
        Wcat[idx] = (k < 64) ? Wih[gc*64 + k] : Whh[gc*64 + (k - 64)];
    }
    if (idx < 256) bc[idx] = bih[idx] + bhh[idx];
}

// ---------------- LSTM: 3 steps fused, c in regs, h in LDS ----------------
// batch b = s*NN + n ; x_t[b] = h2[s][g=t][n][:]

__global__ __launch_bounds__(256) void lstm_kernel(const float* __restrict__ h2,
                                                   const float* __restrict__ Wcat,
                                                   const float* __restrict__ bc,
                                                   float* __restrict__ out){
    __shared__ float sZ[128*LDT]; // [k][r], k<64: x_t, k>=64: h_{t-1}; ~34.8 KB
    int tid = threadIdx.x;
    int b0 = blockIdx.x * 64;
    int tx = tid & 15, ty = tid >> 4;
    int f0 = tx*4, r0 = ty*4;

    float c[4][4];
    #pragma unroll
    for (int i = 0; i < 4; ++i)
        #pragma unroll
        for (int j = 0; j < 4; ++j) c[i][j] = 0.0f;

    float bb[4][4];
    #pragma unroll
    for (int T = 0; T < 4; ++T){
        float4 t4 = *(const float4*)&bc[T*64 + f0];
        bb[T][0] = t4.x; bb[T][1] = t4.y; bb[T][2] = t4.z; bb[T][3] = t4.w;
    }

    for (int t = 0; t < G; ++t){
        // stage x_t transposed into sZ[0..63][r]
        for (int idx = tid; idx < 64*16; idx += 256){
            int r = idx >> 4, fq = idx & 15;
            int b = b0 + r;
            int s = b / NN, n = b - s*NN;
            float4 v = *(const float4*)&h2[((size_t)(s*G + t)*NN + n)*D + fq*4];
            sZ[(fq*4+0)*LDT + r] = v.x;
            sZ[(fq*4+1)*LDT + r] = v.y;
            sZ[(fq*4+2)*LDT + r] = v.z;
            sZ[(fq*4+3)*LDT + r] = v.w;
        }
        __syncthreads();

        int kmax = (t == 0) ? 64 : 128;  // h_0 == 0, skip h-half
        float acc[4][4][4]; // [gate-type T][row i][feat j]
        #pragma unroll
        for (int T = 0; T < 4; ++T)
            #pragma unroll
            for (int i = 0; i < 4; ++i)
                #pragma unroll
                for (int j = 0; j < 4; ++j) acc[T][i][j] = 0.0f;

        #pragma unroll 2
        for (int k = 0; k < kmax; ++k){
            float4 za4 = *(const float4*)&sZ[k*LDT + r0];
            float za[4] = {za4.x, za4.y, za4.z, za4.w};
            #pragma unroll
            for (int T = 0; T < 4; ++T){
                float4 w4 = *(const float4*)&Wcat[k*256 + T*64 + f0];
                float w[4] = {w4.x, w4.y, w4.z, w4.w};
                #pragma unroll
                for (int i = 0; i < 4; ++i)
                    #pragma unroll
                    for (int j = 0; j < 4; ++j)
                        acc[T][i][j] = fmaf(za[i], w[j], acc[T][i][j]);
            }
        }
        __syncthreads(); // everyone done reading sZ before h overwrite

        float hn[4][4];
        #pragma unroll
        for (int i = 0; i < 4; ++i)
            #pragma unroll
            for (int j = 0; j < 4; ++j){
                float ig = sigmf(acc[0][i][j] + bb[0][j]);
                float fg = sigmf(acc[1][i][j] + bb[1][j]);
                float gg = tanhf(acc[2][i][j] + bb[2][j]);
                float og = sigmf(acc[3][i][j] + bb[3][j]);
                float cn = fg*c[i][j] + ig*gg;
                c[i][j] = cn;
                float hv = og * tanhf(cn);
                hn[i][j] = hv;
                if (t < G-1) sZ[(64 + f0 + j)*LDT + (r0 + i)] = hv;
            }
        if (t == G-1){
            #pragma unroll
            for (int i = 0; i < 4; ++i){
                float4 o; o.x = hn[i][0]; o.y = hn[i][1]; o.z = hn[i][2]; o.w = hn[i][3];
                *(float4*)&out[(size_t)(b0 + r0 + i)*D + f0] = o;
            }
        }
        // next staging writes only the x-half; h-writes become visible at the
        // post-staging __syncthreads before anyone reads them.
    }
}

// ---------------- host ----------------

extern "C" void kernel_launch(void* const* d_in, const int* in_sizes, int n_in,
                              void* d_out, int out_size, void* d_ws, size_t ws_size,
                              hipStream_t stream) {
    const float* x   = (const float*)d_in[0];
    const int*   ei  = (const int*)  d_in[1];
    const float* W1l = (const float*)d_in[2];
    const float* W1r = (const float*)d_in[3];
    const float* b1  = (const float*)d_in[4];
    const float* W2l = (const float*)d_in[5];
    const float* W2r = (const float*)d_in[6];
    const float* b2  = (const float*)d_in[7];
    const float* Wih = (const float*)d_in[8];
    const float* Whh = (const float*)d_in[9];
    const float* bih = (const float*)d_in[10];
    const float* bhh = (const float*)d_in[11];
    float* out = (float*)d_out;

    char* ws = (char*)d_ws;
    size_t cur = 0;
    auto alloc = [&](size_t bytes)->void*{
        cur = (cur + 255) & ~(size_t)255;
        void* p = ws + cur; cur += bytes; return p;
    };
    int*   deg    = (int*)  alloc((size_t)SG*NN*4);
    int*   off    = (int*)  alloc((size_t)SG*(NN+1)*4);
    int*   cursor = (int*)  alloc((size_t)SG*NN*4);
    int*   csr    = (int*)  alloc((size_t)SG*EE*4);
    float* h1     = (float*)alloc((size_t)SG*NN*D*4);
    float* h2     = (float*)alloc((size_t)SG*NN*D*4);
    float* Wcat   = (float*)alloc((size_t)128*256*4);
    float* bc     = (float*)alloc((size_t)256*4);
    (void)ws_size; (void)in_sizes; (void)n_in; (void)out_size;
    // total ws use ~141.3 MB

    hipMemsetAsync(deg, 0, (size_t)SG*NN*4, stream);

    const int totE = SG*EE;
    count_kernel<<<(totE + 255)/256, 256, 0, stream>>>(ei, deg);
    scan_kernel <<<SG, 256, 0, stream>>>(deg, off, cursor);
    fill_kernel <<<(totE + 255)/256, 256, 0, stream>>>(ei, cursor, csr);

    dim3 lgrid((NN + 63)/64, SG);
    layer_kernel<<<lgrid, 256, 0, stream>>>(x,  off, csr, W1l, W1r, b1, h1);
    layer_kernel<<<lgrid, 256, 0, stream>>>(h1, off, csr, W2l, W2r, b2, h2);

    wprep_kernel<<<128, 256, 0, stream>>>(Wih, Whh, bih, bhh, Wcat, bc);
    lstm_kernel <<<(S*NN)/64, 256, 0, stream>>>(h2, Wcat, bc, out);
}

// Round 4
// 1093.297 us; speedup vs baseline: 2.1450x; 1.0839x over previous
//
#include <hip/hip_runtime.h>
#include <math.h>

#define S 4
#define G 3
#define NN 20000
#define EE 320000
#define D 64
#define SG (S*G)

static __device__ __forceinline__ float sigmf(float x){ return 1.0f/(1.0f + __expf(-x)); }

// ---------------- CSR build ----------------

__global__ __launch_bounds__(256) void count_kernel(const int* __restrict__ ei, int* __restrict__ deg){
    int idx = blockIdx.x*256 + threadIdx.x;
    const int tot = SG*EE;
    if (idx >= tot) return;
    int sg = idx / EE, e = idx - sg*EE;
    int dst = ei[(sg*2 + 1)*EE + e];
    atomicAdd(&deg[sg*NN + dst], 1);
}

__global__ __launch_bounds__(256) void scan_kernel(const int* __restrict__ deg,
                                                   int* __restrict__ off,
                                                   int* __restrict__ cursor){
    const int CH = (NN + 255)/256; // 79
    int sg = blockIdx.x, t = threadIdx.x;
    int base = sg*NN, obase = sg*(NN+1);
    int lo = t*CH, hi = min(lo+CH, NN);
    int s = 0;
    for (int i = lo; i < hi; ++i) s += deg[base+i];
    __shared__ int sums[256];
    sums[t] = s; __syncthreads();
    for (int ofs = 1; ofs < 256; ofs <<= 1){
        int v = (t >= ofs) ? sums[t-ofs] : 0;
        __syncthreads();
        sums[t] += v;
        __syncthreads();
    }
    int start = sums[t] - s;  // exclusive prefix at chunk start
    for (int i = lo; i < hi; ++i){
        off[obase+i] = start;
        cursor[base+i] = start;
        start += deg[base+i];
    }
    if (lo < NN && hi == NN) off[obase+NN] = start; // == EE
}

__global__ __launch_bounds__(256) void fill_kernel(const int* __restrict__ ei,
                                                   int* __restrict__ cursor,
                                                   int* __restrict__ csr){
    int idx = blockIdx.x*256 + threadIdx.x;
    const int tot = SG*EE;
    if (idx >= tot) return;
    int sg = idx / EE, e = idx - sg*EE;
    int src = ei[(sg*2 + 0)*EE + e];
    int dst = ei[(sg*2 + 1)*EE + e];
    int slot = atomicAdd(&cursor[sg*NN + dst], 1);
    csr[(size_t)sg*EE + slot] = src;
}

// ---------------- SAGE layer: aggregate(mean via CSR) + GEMM + tanh ----------------
// out[sg][i][c] = tanh( mean[i][:] @ Wl[g] + in[i][:] @ Wr[g] + b[g] )
// Row-major LDS tiles; W staged in LDS per 16-k tile.

#define LDX 68    // 68%4==0 (b128-aligned rows), 68%32==4 (bank stagger)

__global__ __launch_bounds__(256) void layer_kernel(const float* __restrict__ in,
                                                    const int* __restrict__ off,
                                                    const int* __restrict__ csr,
                                                    const float* __restrict__ Wl,
                                                    const float* __restrict__ Wr,
                                                    const float* __restrict__ bias,
                                                    float* __restrict__ out){
    __shared__ float sXr[64*LDX];   // x tile, row-major [r][k]      17.4 KB
    __shared__ float sMr[64*LDX];   // mean tile, row-major [r][k]   17.4 KB
    __shared__ float sWt[16*LDX];   // W k-tile [kk][c]               4.4 KB  -> 39.2 KB total, 4 blocks/CU

    int tile = blockIdx.x, sg = blockIdx.y;
    int g = sg % G;
    int tid = threadIdx.x;
    int row0 = tile*64;
    const float* inb = in + (size_t)sg*NN*D;

    // stage x tile row-major (float4 in, float4 out)
    for (int idx = tid; idx < 64*16; idx += 256){
        int r = idx >> 4, fq = idx & 15;
        int i = row0 + r;
        float4 v = {0,0,0,0};
        if (i < NN) v = *(const float4*)&inb[(size_t)i*D + fq*4];
        *(float4*)&sXr[r*LDX + fq*4] = v;
    }

    // aggregate mean: wave per 16 rows; 4 neighbor-groups x 16 lanes x float4; 4 gathers in flight
    {
        int wave = tid >> 6, lane = tid & 63;
        int grp = lane >> 4, fq = lane & 15, fb = fq*4;
        const int* offb = off + sg*(NN+1);
        const int* csrb = csr + (size_t)sg*EE;
        int i0 = row0 + wave*16;
        int ov = offb[min(i0 + lane, NN)];
        for (int r = 0; r < 16; ++r){
            int a   = __shfl(ov, r,   64);
            int b   = __shfl(ov, r+1, 64);
            int deg = b - a;
            float4 acc = {0.0f, 0.0f, 0.0f, 0.0f};
            for (int base = 0; base < deg; base += 64){
                int m = min(deg - base, 64);
                int cv = (lane < m) ? csrb[a + base + lane] : 0;
                int nit = (m + 7) >> 3;
                for (int it = 0; it < nit; it += 2){
                    int p0 = it*8 + grp;
                    int p1 = it*8 + 4 + grp;
                    int p2 = p0 + 8;
                    int p3 = p1 + 8;
                    int n0 = __shfl(cv, p0, 64);
                    int n1 = __shfl(cv, p1, 64);
                    int n2 = __shfl(cv, p2, 64);
                    int n3 = __shfl(cv, p3, 64);
                    float4 v0={0,0,0,0}, v1={0,0,0,0}, v2={0,0,0,0}, v3={0,0,0,0};
                    if (p0 < m) v0 = *(const float4*)&inb[(size_t)n0*D + fb];
                    if (p1 < m) v1 = *(const float4*)&inb[(size_t)n1*D + fb];
                    if (p2 < m) v2 = *(const float4*)&inb[(size_t)n2*D + fb];
                    if (p3 < m) v3 = *(const float4*)&inb[(size_t)n3*D + fb];
                    acc.x += (v0.x + v1.x) + (v2.x + v3.x);
                    acc.y += (v0.y + v1.y) + (v2.y + v3.y);
                    acc.z += (v0.z + v1.z) + (v2.z + v3.z);
                    acc.w += (v0.w + v1.w) + (v2.w + v3.w);
                }
            }
            acc.x += __shfl_xor(acc.x, 16, 64);
            acc.y += __shfl_xor(acc.y, 16, 64);
            acc.z += __shfl_xor(acc.z, 16, 64);
            acc.w += __shfl_xor(acc.w, 16, 64);
            acc.x += __shfl_xor(acc.x, 32, 64);
            acc.y += __shfl_xor(acc.y, 32, 64);
            acc.z += __shfl_xor(acc.z, 32, 64);
            acc.w += __shfl_xor(acc.w, 32, 64);
            float inv = (deg > 0) ? (1.0f/(float)deg) : 0.0f;
            if (grp == 0){
                float4 mres;
                mres.x = acc.x*inv; mres.y = acc.y*inv; mres.z = acc.z*inv; mres.w = acc.w*inv;
                *(float4*)&sMr[(wave*16 + r)*LDX + fb] = mres;
            }
        }
    }

    int tx = tid & 15, ty = tid >> 4;
    int c0 = tx*4, r0 = ty*4;
    float acc[4][4];
    #pragma unroll
    for (int i = 0; i < 4; ++i)
        #pragma unroll
        for (int j = 0; j < 4; ++j) acc[i][j] = 0.0f;

    const float* Wlg = Wl + (size_t)g*64*64;
    const float* Wrg = Wr + (size_t)g*64*64;

    #pragma unroll 1
    for (int pass = 0; pass < 2; ++pass){
        const float* Wsrc = (pass == 0) ? Wlg : Wrg;
        #pragma unroll 1
        for (int kt = 0; kt < 4; ++kt){
            __syncthreads();   // first one doubles as post-aggregation/staging barrier
            {   // stage sWt: 16 k-rows x 64 cols, one float4 per thread
                int kk = tid >> 4, cc = (tid & 15)*4;
                *(float4*)&sWt[kk*LDX + cc] = *(const float4*)&Wsrc[(kt*16 + kk)*64 + cc];
            }
            __syncthreads();
            #pragma unroll
            for (int k4 = 0; k4 < 4; ++k4){
                float a_[4][4];
                #pragma unroll
                for (int i = 0; i < 4; ++i){
                    const float* A = (pass == 0) ? &sMr[(r0+i)*LDX + kt*16 + k4*4]
                                                 : &sXr[(r0+i)*LDX + kt*16 + k4*4];
                    float4 t4 = *(const float4*)A;
                    a_[i][0]=t4.x; a_[i][1]=t4.y; a_[i][2]=t4.z; a_[i][3]=t4.w;
                }
                #pragma unroll
                for (int kk = 0; kk < 4; ++kk){
                    float4 w4 = *(const float4*)&sWt[(k4*4 + kk)*LDX + c0];
                    float w[4] = {w4.x, w4.y, w4.z, w4.w};
                    #pragma unroll
                    for (int i = 0; i < 4; ++i)
                        #pragma unroll
                        for (int j = 0; j < 4; ++j)
                            acc[i][j] = fmaf(a_[i][kk], w[j], acc[i][j]);
                }
            }
        }
    }

    float4 b4 = *(const float4*)&bias[g*64 + c0];
    float bv[4] = {b4.x, b4.y, b4.z, b4.w};
    float* outb = out + (size_t)sg*NN*D;
    #pragma unroll
    for (int i = 0; i < 4; ++i){
        int r = row0 + r0 + i;
        if (r < NN){
            float4 o;
            o.x = tanhf(acc[i][0] + bv[0]);
            o.y = tanhf(acc[i][1] + bv[1]);
            o.z = tanhf(acc[i][2] + bv[2]);
            o.w = tanhf(acc[i][3] + bv[3]);
            *(float4*)&outb[(size_t)r*D + c0] = o;
        }
    }
}

// ---------------- LSTM weight prep: Wcat[k][gate], bc = bih+bhh ----------------

__global__ __launch_bounds__(256) void wprep_kernel(const float* __restrict__ Wih,
                                                    const float* __restrict__ Whh,
                                                    const float* __restrict__ bih,
                                                    const float* __restrict__ bhh,
                                                    float* __restrict__ Wcat,
                                                    float* __restrict__ bc){
    int idx = blockIdx.x*256 + threadIdx.x;
    if (idx < 128*256){
        int k = idx >> 8, gc = idx & 255;
        Wcat[idx] = (k < 64) ? Wih[gc*64 + k] : Whh[gc*64 + (k - 64)];
    }
    if (idx < 256) bc[idx] = bih[idx] + bhh[idx];
}

// ---------------- LSTM: 3 steps fused, c in regs, h in LDS, W k-tiled in LDS ----------------
// batch b = s*NN + n ; x_t[b] = h2[s][g=t][n][:]

#define LDZ 132   // row-major [r][k], k<64: x_t, k>=64: h_{t-1}
#define LDW 260   // sWt rows: 256 gate-cols + pad

__global__ __launch_bounds__(256) void lstm_kernel(const float* __restrict__ h2,
                                                   const float* __restrict__ Wcat,
                                                   const float* __restrict__ bc,
                                                   float* __restrict__ out){
    __shared__ float sZr[64*LDZ];   // 33.8 KB
    __shared__ float sWt[16*LDW];   // 16.6 KB -> 50.4 KB total, 3 blocks/CU
    int tid = threadIdx.x;
    int b0 = blockIdx.x * 64;
    int tx = tid & 15, ty = tid >> 4;
    int f0 = tx*4, r0 = ty*4;

    float c[4][4];
    #pragma unroll
    for (int i = 0; i < 4; ++i)
        #pragma unroll
        for (int j = 0; j < 4; ++j) c[i][j] = 0.0f;

    float bb[4][4];
    #pragma unroll
    for (int T = 0; T < 4; ++T){
        float4 t4 = *(const float4*)&bc[T*64 + f0];
        bb[T][0] = t4.x; bb[T][1] = t4.y; bb[T][2] = t4.z; bb[T][3] = t4.w;
    }

    for (int t = 0; t < G; ++t){
        // stage x_t row-major into sZr[r][0..63]
        for (int idx = tid; idx < 64*16; idx += 256){
            int r = idx >> 4, fq = idx & 15;
            int b = b0 + r;
            int s = b / NN, n = b - s*NN;
            float4 v = *(const float4*)&h2[((size_t)(s*G + t)*NN + n)*D + fq*4];
            *(float4*)&sZr[r*LDZ + fq*4] = v;
        }

        int ktiles = (t == 0) ? 4 : 8;  // h_0 == 0, skip h-half
        float acc[4][4][4]; // [gate T][row i][feat j]
        #pragma unroll
        for (int T = 0; T < 4; ++T)
            #pragma unroll
            for (int i = 0; i < 4; ++i)
                #pragma unroll
                for (int j = 0; j < 4; ++j) acc[T][i][j] = 0.0f;

        #pragma unroll 1
        for (int kt = 0; kt < ktiles; ++kt){
            __syncthreads();   // staged data (x / h / prev sWt consumers) visible
            // stage sWt: 16 k-rows x 256 gate-cols = 1024 float4, 4 per thread
            for (int idx = tid; idx < 1024; idx += 256){
                int kk = idx >> 6, cc = (idx & 63)*4;
                *(float4*)&sWt[kk*LDW + cc] = *(const float4*)&Wcat[(kt*16 + kk)*256 + cc];
            }
            __syncthreads();
            #pragma unroll
            for (int k4 = 0; k4 < 4; ++k4){
                float a_[4][4];
                #pragma unroll
                for (int i = 0; i < 4; ++i){
                    float4 t4 = *(const float4*)&sZr[(r0+i)*LDZ + kt*16 + k4*4];
                    a_[i][0]=t4.x; a_[i][1]=t4.y; a_[i][2]=t4.z; a_[i][3]=t4.w;
                }
                #pragma unroll
                for (int kk = 0; kk < 4; ++kk){
                    #pragma unroll
                    for (int T = 0; T < 4; ++T){
                        float4 w4 = *(const float4*)&sWt[(k4*4 + kk)*LDW + T*64 + f0];
                        float w[4] = {w4.x, w4.y, w4.z, w4.w};
                        #pragma unroll
                        for (int i = 0; i < 4; ++i)
                            #pragma unroll
                            for (int j = 0; j < 4; ++j)
                                acc[T][i][j] = fmaf(a_[i][kk], w[j], acc[T][i][j]);
                    }
                }
            }
        }
        __syncthreads(); // all waves done reading sZr before h overwrite

        float hn[4][4];
        #pragma unroll
        for (int i = 0; i < 4; ++i)
            #pragma unroll
            for (int j = 0; j < 4; ++j){
                float ig = sigmf(acc[0][i][j] + bb[0][j]);
                float fg = sigmf(acc[1][i][j] + bb[1][j]);
                float gg = tanhf(acc[2][i][j] + bb[2][j]);
                float og = sigmf(acc[3][i][j] + bb[3][j]);
                float cn = fg*c[i][j] + ig*gg;
                c[i][j] = cn;
                hn[i][j] = og * tanhf(cn);
            }
        if (t < G-1){
            #pragma unroll
            for (int i = 0; i < 4; ++i){
                float4 o; o.x = hn[i][0]; o.y = hn[i][1]; o.z = hn[i][2]; o.w = hn[i][3];
                *(float4*)&sZr[(r0+i)*LDZ + 64 + f0] = o;  // h-half; visible at next kt barrier
            }
        } else {
            #pragma unroll
            for (int i = 0; i < 4; ++i){
                float4 o; o.x = hn[i][0]; o.y = hn[i][1]; o.z = hn[i][2]; o.w = hn[i][3];
                *(float4*)&out[(size_t)(b0 + r0 + i)*D + f0] = o;
            }
        }
    }
}

// ---------------- host ----------------

extern "C" void kernel_launch(void* const* d_in, const int* in_sizes, int n_in,
                              void* d_out, int out_size, void* d_ws, size_t ws_size,
                              hipStream_t stream) {
    const float* x   = (const float*)d_in[0];
    const int*   ei  = (const int*)  d_in[1];
    const float* W1l = (const float*)d_in[2];
    const float* W1r = (const float*)d_in[3];
    const float* b1  = (const float*)d_in[4];
    const float* W2l = (const float*)d_in[5];
    const float* W2r = (const float*)d_in[6];
    const float* b2  = (const float*)d_in[7];
    const float* Wih = (const float*)d_in[8];
    const float* Whh = (const float*)d_in[9];
    const float* bih = (const float*)d_in[10];
    const float* bhh = (const float*)d_in[11];
    float* out = (float*)d_out;

    char* ws = (char*)d_ws;
    size_t cur = 0;
    auto alloc = [&](size_t bytes)->void*{
        cur = (cur + 255) & ~(size_t)255;
        void* p = ws + cur; cur += bytes; return p;
    };
    int*   deg    = (int*)  alloc((size_t)SG*NN*4);
    int*   off    = (int*)  alloc((size_t)SG*(NN+1)*4);
    int*   cursor = (int*)  alloc((size_t)SG*NN*4);
    int*   csr    = (int*)  alloc((size_t)SG*EE*4);
    float* h1     = (float*)alloc((size_t)SG*NN*D*4);
    float* h2     = (float*)alloc((size_t)SG*NN*D*4);
    float* Wcat   = (float*)alloc((size_t)128*256*4);
    float* bc     = (float*)alloc((size_t)256*4);
    (void)ws_size; (void)in_sizes; (void)n_in; (void)out_size;

    (void)hipMemsetAsync(deg, 0, (size_t)SG*NN*4, stream);

    const int totE = SG*EE;
    count_kernel<<<(totE + 255)/256, 256, 0, stream>>>(ei, deg);
    scan_kernel <<<SG, 256, 0, stream>>>(deg, off, cursor);
    fill_kernel <<<(totE + 255)/256, 256, 0, stream>>>(ei, cursor, csr);

    dim3 lgrid((NN + 63)/64, SG);
    layer_kernel<<<lgrid, 256, 0, stream>>>(x,  off, csr, W1l, W1r, b1, h1);
    layer_kernel<<<lgrid, 256, 0, stream>>>(h1, off, csr, W2l, W2r, b2, h2);

    wprep_kernel<<<128, 256, 0, stream>>>(Wih, Whh, bih, bhh, Wcat, bc);
    lstm_kernel <<<(S*NN)/64, 256, 0, stream>>>(h2, Wcat, bc, out);
}

// Round 5
// 1008.351 us; speedup vs baseline: 2.3257x; 1.0842x over previous
//
#include <hip/hip_runtime.h>
#include <math.h>

#define S 4
#define G 3
#define NN 20000
#define EE 320000
#define D 64
#define SG (S*G)

static __device__ __forceinline__ float sigmf(float x){ return 1.0f/(1.0f + __expf(-x)); }

// float -> bf16 bits, round-nearest-even
static __device__ __forceinline__ unsigned short f2bf(float f){
    union { float f; unsigned u; } v; v.f = f;
    unsigned r = v.u + 0x7FFF + ((v.u >> 16) & 1);
    return (unsigned short)(r >> 16);
}

typedef short bf16x8 __attribute__((ext_vector_type(8)));
typedef float f32x4  __attribute__((ext_vector_type(4)));

// ---------------- CSR build ----------------

__global__ __launch_bounds__(256) void count_kernel(const int* __restrict__ ei, int* __restrict__ deg){
    int idx = blockIdx.x*256 + threadIdx.x;
    const int tot = SG*EE;
    if (idx >= tot) return;
    int sg = idx / EE, e = idx - sg*EE;
    int dst = ei[(sg*2 + 1)*EE + e];
    atomicAdd(&deg[sg*NN + dst], 1);
}

__global__ __launch_bounds__(256) void scan_kernel(const int* __restrict__ deg,
                                                   int* __restrict__ off,
                                                   int* __restrict__ cursor){
    const int CH = (NN + 255)/256; // 79
    int sg = blockIdx.x, t = threadIdx.x;
    int base = sg*NN, obase = sg*(NN+1);
    int lo = t*CH, hi = min(lo+CH, NN);
    int s = 0;
    for (int i = lo; i < hi; ++i) s += deg[base+i];
    __shared__ int sums[256];
    sums[t] = s; __syncthreads();
    for (int ofs = 1; ofs < 256; ofs <<= 1){
        int v = (t >= ofs) ? sums[t-ofs] : 0;
        __syncthreads();
        sums[t] += v;
        __syncthreads();
    }
    int start = sums[t] - s;  // exclusive prefix at chunk start
    for (int i = lo; i < hi; ++i){
        off[obase+i] = start;
        cursor[base+i] = start;
        start += deg[base+i];
    }
    if (lo < NN && hi == NN) off[obase+NN] = start; // == EE
}

__global__ __launch_bounds__(256) void fill_kernel(const int* __restrict__ ei,
                                                   int* __restrict__ cursor,
                                                   int* __restrict__ csr){
    int idx = blockIdx.x*256 + threadIdx.x;
    const int tot = SG*EE;
    if (idx >= tot) return;
    int sg = idx / EE, e = idx - sg*EE;
    int src = ei[(sg*2 + 0)*EE + e];
    int dst = ei[(sg*2 + 1)*EE + e];
    int slot = atomicAdd(&cursor[sg*NN + dst], 1);
    csr[(size_t)sg*EE + slot] = src;
}

// ---------------- SAGE layer: aggregate(mean via CSR) + GEMM + tanh ----------------
// out[sg][i][c] = tanh( mean[i][:] @ Wl[g] + in[i][:] @ Wr[g] + b[g] )

#define LDX 68    // 68%4==0 (b128-aligned rows), 68%32==4 (bank stagger)

__global__ __launch_bounds__(256) void layer_kernel(const float* __restrict__ in,
                                                    const int* __restrict__ off,
                                                    const int* __restrict__ csr,
                                                    const float* __restrict__ Wl,
                                                    const float* __restrict__ Wr,
                                                    const float* __restrict__ bias,
                                                    float* __restrict__ out){
    __shared__ float sXr[64*LDX];   // x tile, row-major [r][k]      17.4 KB
    __shared__ float sMr[64*LDX];   // mean tile, row-major [r][k]   17.4 KB
    __shared__ float sWt[16*LDX];   // W k-tile [kk][c]               4.4 KB

    int tile = blockIdx.x, sg = blockIdx.y;
    int g = sg % G;
    int tid = threadIdx.x;
    int row0 = tile*64;
    const float* inb = in + (size_t)sg*NN*D;

    // stage x tile row-major (float4 in, float4 out)
    for (int idx = tid; idx < 64*16; idx += 256){
        int r = idx >> 4, fq = idx & 15;
        int i = row0 + r;
        float4 v = {0,0,0,0};
        if (i < NN) v = *(const float4*)&inb[(size_t)i*D + fq*4];
        *(float4*)&sXr[r*LDX + fq*4] = v;
    }

    // aggregate mean: wave per 16 rows; 4 neighbor-groups x 16 lanes x float4; 4 gathers in flight
    {
        int wave = tid >> 6, lane = tid & 63;
        int grp = lane >> 4, fq = lane & 15, fb = fq*4;
        const int* offb = off + sg*(NN+1);
        const int* csrb = csr + (size_t)sg*EE;
        int i0 = row0 + wave*16;
        int ov = offb[min(i0 + lane, NN)];
        for (int r = 0; r < 16; ++r){
            int a   = __shfl(ov, r,   64);
            int b   = __shfl(ov, r+1, 64);
            int deg = b - a;
            float4 acc = {0.0f, 0.0f, 0.0f, 0.0f};
            for (int base = 0; base < deg; base += 64){
                int m = min(deg - base, 64);
                int cv = (lane < m) ? csrb[a + base + lane] : 0;
                int nit = (m + 7) >> 3;
                for (int it = 0; it < nit; it += 2){
                    int p0 = it*8 + grp;
                    int p1 = it*8 + 4 + grp;
                    int p2 = p0 + 8;
                    int p3 = p1 + 8;
                    int n0 = __shfl(cv, p0, 64);
                    int n1 = __shfl(cv, p1, 64);
                    int n2 = __shfl(cv, p2, 64);
                    int n3 = __shfl(cv, p3, 64);
                    float4 v0={0,0,0,0}, v1={0,0,0,0}, v2={0,0,0,0}, v3={0,0,0,0};
                    if (p0 < m) v0 = *(const float4*)&inb[(size_t)n0*D + fb];
                    if (p1 < m) v1 = *(const float4*)&inb[(size_t)n1*D + fb];
                    if (p2 < m) v2 = *(const float4*)&inb[(size_t)n2*D + fb];
                    if (p3 < m) v3 = *(const float4*)&inb[(size_t)n3*D + fb];
                    acc.x += (v0.x + v1.x) + (v2.x + v3.x);
                    acc.y += (v0.y + v1.y) + (v2.y + v3.y);
                    acc.z += (v0.z + v1.z) + (v2.z + v3.z);
                    acc.w += (v0.w + v1.w) + (v2.w + v3.w);
                }
            }
            acc.x += __shfl_xor(acc.x, 16, 64);
            acc.y += __shfl_xor(acc.y, 16, 64);
            acc.z += __shfl_xor(acc.z, 16, 64);
            acc.w += __shfl_xor(acc.w, 16, 64);
            acc.x += __shfl_xor(acc.x, 32, 64);
            acc.y += __shfl_xor(acc.y, 32, 64);
            acc.z += __shfl_xor(acc.z, 32, 64);
            acc.w += __shfl_xor(acc.w, 32, 64);
            float inv = (deg > 0) ? (1.0f/(float)deg) : 0.0f;
            if (grp == 0){
                float4 mres;
                mres.x = acc.x*inv; mres.y = acc.y*inv; mres.z = acc.z*inv; mres.w = acc.w*inv;
                *(float4*)&sMr[(wave*16 + r)*LDX + fb] = mres;
            }
        }
    }

    int tx = tid & 15, ty = tid >> 4;
    int c0 = tx*4, r0 = ty*4;
    float acc[4][4];
    #pragma unroll
    for (int i = 0; i < 4; ++i)
        #pragma unroll
        for (int j = 0; j < 4; ++j) acc[i][j] = 0.0f;

    const float* Wlg = Wl + (size_t)g*64*64;
    const float* Wrg = Wr + (size_t)g*64*64;

    #pragma unroll 1
    for (int pass = 0; pass < 2; ++pass){
        const float* Wsrc = (pass == 0) ? Wlg : Wrg;
        #pragma unroll 1
        for (int kt = 0; kt < 4; ++kt){
            __syncthreads();   // first one doubles as post-aggregation/staging barrier
            {   // stage sWt: 16 k-rows x 64 cols, one float4 per thread
                int kk = tid >> 4, cc = (tid & 15)*4;
                *(float4*)&sWt[kk*LDX + cc] = *(const float4*)&Wsrc[(kt*16 + kk)*64 + cc];
            }
            __syncthreads();
            #pragma unroll
            for (int k4 = 0; k4 < 4; ++k4){
                float a_[4][4];
                #pragma unroll
                for (int i = 0; i < 4; ++i){
                    const float* A = (pass == 0) ? &sMr[(r0+i)*LDX + kt*16 + k4*4]
                                                 : &sXr[(r0+i)*LDX + kt*16 + k4*4];
                    float4 t4 = *(const float4*)A;
                    a_[i][0]=t4.x; a_[i][1]=t4.y; a_[i][2]=t4.z; a_[i][3]=t4.w;
                }
                #pragma unroll
                for (int kk = 0; kk < 4; ++kk){
                    float4 w4 = *(const float4*)&sWt[(k4*4 + kk)*LDX + c0];
                    float w[4] = {w4.x, w4.y, w4.z, w4.w};
                    #pragma unroll
                    for (int i = 0; i < 4; ++i)
                        #pragma unroll
                        for (int j = 0; j < 4; ++j)
                            acc[i][j] = fmaf(a_[i][kk], w[j], acc[i][j]);
                }
            }
        }
    }

    float4 b4 = *(const float4*)&bias[g*64 + c0];
    float bv[4] = {b4.x, b4.y, b4.z, b4.w};
    float* outb = out + (size_t)sg*NN*D;
    #pragma unroll
    for (int i = 0; i < 4; ++i){
        int r = row0 + r0 + i;
        if (r < NN){
            float4 o;
            o.x = tanhf(acc[i][0] + bv[0]);
            o.y = tanhf(acc[i][1] + bv[1]);
            o.z = tanhf(acc[i][2] + bv[2]);
            o.w = tanhf(acc[i][3] + bv[3]);
            *(float4*)&outb[(size_t)r*D + c0] = o;
        }
    }
}

// ---------------- LSTM weight prep: Wt[col][k] bf16 (k = x||h), bc = bih+bhh ----------------

__global__ __launch_bounds__(256) void wprep_kernel(const float* __restrict__ Wih,
                                                    const float* __restrict__ Whh,
                                                    const float* __restrict__ bih,
                                                    const float* __restrict__ bhh,
                                                    unsigned short* __restrict__ Wt,
                                                    float* __restrict__ bc){
    int idx = blockIdx.x*256 + threadIdx.x;
    if (idx < 256*128){
        int col = idx >> 7, k = idx & 127;
        float v = (k < 64) ? Wih[col*64 + k] : Whh[col*64 + (k - 64)];
        Wt[idx] = f2bf(v);
    }
    if (idx < 256) bc[idx] = bih[idx] + bhh[idx];
}

// ---------------- LSTM: 3 steps fused, MFMA bf16 gate GEMM ----------------
// batch b = s*NN + n ; x_t[b] = h2[s][g=t][n][:]
// A (x||h) bf16 in LDS [row][k]; B = Wt[col][k] bf16 from global (L1/L2-hot).
// Wave w -> rows 16w..16w+15, 16 col-tiles of 16. C/D: col=lane&15, row=quad*4+reg.

#define LDA 136   // ushort pitch; 272 B rows, 16 B-aligned

__global__ __launch_bounds__(256) void lstm_kernel(const float* __restrict__ h2,
                                                   const unsigned short* __restrict__ Wt,
                                                   const float* __restrict__ bc,
                                                   float* __restrict__ out){
    __shared__ unsigned short sA[64*LDA];  // 17.4 KB: k<64 x_t, k>=64 h_{t-1}
    __shared__ float sO[64*68];            // 17.4 KB: fp32 output staging
    int tid = threadIdx.x;
    int b0 = blockIdx.x * 64;
    int wave = tid >> 6, lane = tid & 63;
    int n0 = lane & 15, q = lane >> 4;
    int rbase = wave*16;

    // bias for this lane's 16 (T, j = n0+16m) gate columns
    float bb[4][4];
    #pragma unroll
    for (int T = 0; T < 4; ++T)
        #pragma unroll
        for (int m = 0; m < 4; ++m)
            bb[T][m] = bc[T*64 + n0 + 16*m];

    float c[4][4];  // [reg(row)][m(j)]
    #pragma unroll
    for (int i = 0; i < 4; ++i)
        #pragma unroll
        for (int m = 0; m < 4; ++m) c[i][m] = 0.0f;

    for (int t = 0; t < G; ++t){
        // stage x_t as bf16 into sA[r][0..63]
        for (int idx = tid; idx < 64*16; idx += 256){
            int r = idx >> 4, fq = idx & 15;
            int b = b0 + r;
            int s = b / NN, n = b - s*NN;
            float4 v = *(const float4*)&h2[((size_t)(s*G + t)*NN + n)*D + fq*4];
            union { unsigned short u[4]; double d; } pk;
            pk.u[0] = f2bf(v.x); pk.u[1] = f2bf(v.y);
            pk.u[2] = f2bf(v.z); pk.u[3] = f2bf(v.w);
            *(double*)&sA[r*LDA + fq*4] = pk.d;   // 8 B aligned store
        }
        __syncthreads();

        int nkc = (t == 0) ? 2 : 4;   // h_0 == 0: skip h-half k-chunks
        f32x4 accv[16];
        #pragma unroll
        for (int ct = 0; ct < 16; ++ct) accv[ct] = (f32x4){0.f,0.f,0.f,0.f};

        #pragma unroll 1
        for (int kc = 0; kc < nkc; ++kc){
            bf16x8 af = *(const bf16x8*)&sA[(rbase + n0)*LDA + kc*32 + q*8];
            #pragma unroll
            for (int ct = 0; ct < 16; ++ct){
                bf16x8 bf = *(const bf16x8*)&Wt[(ct*16 + n0)*128 + kc*32 + q*8];
                accv[ct] = __builtin_amdgcn_mfma_f32_16x16x32_bf16(af, bf, accv[ct], 0, 0, 0);
            }
        }
        __syncthreads();  // all waves done reading sA before h overwrite

        // elementwise: lane owns rows rbase+q*4+reg, cols j = n0+16m (all 4 gates local)
        #pragma unroll
        for (int reg = 0; reg < 4; ++reg){
            int r = rbase + q*4 + reg;
            #pragma unroll
            for (int m = 0; m < 4; ++m){
                float ig = sigmf(accv[0*4 + m][reg] + bb[0][m]);
                float fg = sigmf(accv[1*4 + m][reg] + bb[1][m]);
                float gg = tanhf(accv[2*4 + m][reg] + bb[2][m]);
                float og = sigmf(accv[3*4 + m][reg] + bb[3][m]);
                float cn = fg*c[reg][m] + ig*gg;
                c[reg][m] = cn;
                float hv = og * tanhf(cn);
                if (t < G-1) sA[r*LDA + 64 + n0 + 16*m] = f2bf(hv);  // h for next step
                else         sO[r*68 + n0 + 16*m] = hv;
            }
        }
        // h/sO writes become visible at the next loop's post-staging barrier /
        // the epilogue barrier below.
    }

    __syncthreads();
    for (int idx = tid; idx < 64*16; idx += 256){
        int r = idx >> 4, fq = idx & 15;
        float4 v = *(const float4*)&sO[r*68 + fq*4];
        *(float4*)&out[(size_t)(b0 + r)*D + fq*4] = v;
    }
}

// ---------------- host ----------------

extern "C" void kernel_launch(void* const* d_in, const int* in_sizes, int n_in,
                              void* d_out, int out_size, void* d_ws, size_t ws_size,
                              hipStream_t stream) {
    const float* x   = (const float*)d_in[0];
    const int*   ei  = (const int*)  d_in[1];
    const float* W1l = (const float*)d_in[2];
    const float* W1r = (const float*)d_in[3];
    const float* b1  = (const float*)d_in[4];
    const float* W2l = (const float*)d_in[5];
    const float* W2r = (const float*)d_in[6];
    const float* b2  = (const float*)d_in[7];
    const float* Wih = (const float*)d_in[8];
    const float* Whh = (const float*)d_in[9];
    const float* bih = (const float*)d_in[10];
    const float* bhh = (const float*)d_in[11];
    float* out = (float*)d_out;

    char* ws = (char*)d_ws;
    size_t cur = 0;
    auto alloc = [&](size_t bytes)->void*{
        cur = (cur + 255) & ~(size_t)255;
        void* p = ws + cur; cur += bytes; return p;
    };
    int*   deg    = (int*)  alloc((size_t)SG*NN*4);
    int*   off    = (int*)  alloc((size_t)SG*(NN+1)*4);
    int*   cursor = (int*)  alloc((size_t)SG*NN*4);
    int*   csr    = (int*)  alloc((size_t)SG*EE*4);
    float* h1     = (float*)alloc((size_t)SG*NN*D*4);
    float* h2     = (float*)alloc((size_t)SG*NN*D*4);
    unsigned short* Wt = (unsigned short*)alloc((size_t)256*128*2);
    float* bc     = (float*)alloc((size_t)256*4);
    (void)ws_size; (void)in_sizes; (void)n_in; (void)out_size;

    (void)hipMemsetAsync(deg, 0, (size_t)SG*NN*4, stream);

    const int totE = SG*EE;
    count_kernel<<<(totE + 255)/256, 256, 0, stream>>>(ei, deg);
    scan_kernel <<<SG, 256, 0, stream>>>(deg, off, cursor);
    fill_kernel <<<(totE + 255)/256, 256, 0, stream>>>(ei, cursor, csr);

    dim3 lgrid((NN + 63)/64, SG);
    layer_kernel<<<lgrid, 256, 0, stream>>>(x,  off, csr, W1l, W1r, b1, h1);
    layer_kernel<<<lgrid, 256, 0, stream>>>(h1, off, csr, W2l, W2r, b2, h2);

    wprep_kernel<<<128, 256, 0, stream>>>(Wih, Whh, bih, bhh, Wt, bc);
    lstm_kernel <<<(S*NN)/64, 256, 0, stream>>>(h2, Wt, bc, out);
}